// Round 1
// baseline (175.308 us; speedup 1.0000x reference)
//
#include <hip/hip_runtime.h>
#include <hip/hip_bf16.h>

// Problem constants
#define BATCH 2
#define SEQ   2048
#define DMODEL 1024
#define NHEADS 16
#define DHEAD  64
#define MTOT   (BATCH * SEQ)         // 4096 rows
#define QKSTR  2048                  // q,k buffer row stride (v stored separately)

typedef __attribute__((ext_vector_type(8))) short bf16x8;   // 8 bf16 in 4 VGPRs
typedef __attribute__((ext_vector_type(4))) float f32x4;

// 16B async global->LDS copy (LDS dest = wave-uniform base + lane*16).
__device__ __forceinline__ void glds16(const void* g, void* l)
{
    __builtin_amdgcn_global_load_lds(
        (const __attribute__((address_space(1))) unsigned int*)g,
        (__attribute__((address_space(3))) unsigned int*)l, 16, 0, 0);
}

// ---------------------------------------------------------------------------
// fused fp32 -> bf16 casts (x, qkv_w, proj_w in one launch)
// ---------------------------------------------------------------------------
__global__ void cast_all_kernel(
    const float* __restrict__ a, __hip_bfloat16* __restrict__ oa, int na4,
    const float* __restrict__ b, __hip_bfloat16* __restrict__ ob, int nb4,
    const float* __restrict__ c, __hip_bfloat16* __restrict__ oc, int nc4)
{
    int i = blockIdx.x * blockDim.x + threadIdx.x;
    const float* src; __hip_bfloat16* dst; int j = i;
    if (j < na4) { src = a; dst = oa; }
    else {
        j -= na4;
        if (j < nb4) { src = b; dst = ob; }
        else {
            j -= nb4;
            if (j >= nc4) return;
            src = c; dst = oc;
        }
    }
    float4 v = ((const float4*)src)[j];
    __hip_bfloat16 tmp[4];
    tmp[0] = __float2bfloat16(v.x);
    tmp[1] = __float2bfloat16(v.y);
    tmp[2] = __float2bfloat16(v.z);
    tmp[3] = __float2bfloat16(v.w);
    *(uint2*)(dst + 4 * (size_t)j) = *(const uint2*)tmp;
}

// ---------------------------------------------------------------------------
// GEMM: out[M,N] = A[M,K] @ W[N,K]^T + bias[N]; bf16 in, fp32 acc.
// 64xTN tile (occupancy lever: qkv 6 blocks/CU, proj 4 blocks/CU), BK=64,
// global_load_lds(16B) staging, XOR-swizzled LDS (chunk ^ (row&7), 64-el rows
// -> conflict-free; r6-verified). Wave partition: wm=(wave&1)*32 (2 m-frags),
// wn=(wave>>1)*(TN/2).
// MODE 0: plain store (stride N). MODE 1 (qkv, TN=128): cols<2048 RoPE pairs
// into qk buffer (stride QKSTR); cols>=2048 V transposed to vtg[(b,h),dh,s].
// ---------------------------------------------------------------------------
#define GTM 64
#define GBK 64

__device__ __forceinline__ void store_out(float* p, float v) { *p = v; }
__device__ __forceinline__ void store_out(__hip_bfloat16* p, float v) { *p = __float2bfloat16(v); }

template <typename OutT, int MODE, int TN>
__global__ __launch_bounds__(256, 6) void gemm_bias_kernel(
    const __hip_bfloat16* __restrict__ A, const __hip_bfloat16* __restrict__ W,
    const float* __restrict__ bias, OutT* __restrict__ out,
    __hip_bfloat16* __restrict__ vtg,
    int M, int N, int K)
{
    const int NI = TN / 32;                    // n-frags per wave
    const int bm = blockIdx.x * GTM;
    const int bn = blockIdx.y * TN;
    const int tid = threadIdx.x;
    const int wave = tid >> 6;
    const int lane = tid & 63;
    const int quad = lane >> 4;
    const int l16 = lane & 15;
    const int wm = (wave & 1) * 32;
    const int wn = (wave >> 1) * (TN / 2);

    __shared__ __hip_bfloat16 As[GTM * GBK];   // 8 KB
    __shared__ __hip_bfloat16 Bs[TN * GBK];    // 16 KB (TN=128) / 8 KB (TN=64)

    f32x4 acc[2][NI] = {};

    const int srow = lane >> 3;
    const int gc8 = (((lane & 7) ^ srow)) * 8;

    for (int kt = 0; kt < K; kt += GBK) {
#pragma unroll
        for (int t = 0; t < 2; t++) {          // A: 8 chunks of 8 rows, 2/wave
            int i = wave * 2 + t;
            glds16(A + (size_t)(bm + i * 8 + srow) * K + kt + gc8, As + i * 512);
        }
#pragma unroll
        for (int t = 0; t < TN / 32; t++) {    // B: TN/8 chunks, (TN/32)/wave
            int i = wave * (TN / 32) + t;
            glds16(W + (size_t)(bn + i * 8 + srow) * K + kt + gc8, Bs + i * 512);
        }
        __syncthreads();

#pragma unroll
        for (int kk = 0; kk < 2; kk++) {
            bf16x8 af[2], bfr[NI];
#pragma unroll
            for (int i = 0; i < 2; i++) {
                int ra = wm + i * 16 + l16;
                af[i] = *(const bf16x8*)(As + ra * 64 + (((kk << 2) + quad) ^ (ra & 7)) * 8);
            }
#pragma unroll
            for (int i = 0; i < NI; i++) {
                int rb = wn + i * 16 + l16;
                bfr[i] = *(const bf16x8*)(Bs + rb * 64 + (((kk << 2) + quad) ^ (rb & 7)) * 8);
            }
#pragma unroll
            for (int mi = 0; mi < 2; mi++)
#pragma unroll
                for (int ni = 0; ni < NI; ni++)
                    acc[mi][ni] = __builtin_amdgcn_mfma_f32_16x16x32_bf16(
                        af[mi], bfr[ni], acc[mi][ni], 0, 0, 0);
        }
        __syncthreads();
    }

    if (MODE == 1 && (bn + wn) < 2 * DMODEL) {
        // q/k columns: RoPE pairs (dh, dh+32) = (acc[.][ni], acc[.][ni+2])
#pragma unroll
        for (int ni = 0; ni < 2; ni++) {
            int col = bn + wn + ni * 16 + l16;
            int i32 = col & 31;
            float invf = exp2f(-13.287712379549449f * (float)i32 * (1.0f / 32.0f));
            float b1 = bias[col], b2 = bias[col + 32];
#pragma unroll
            for (int mi = 0; mi < 2; mi++) {
#pragma unroll
                for (int r = 0; r < 4; r++) {
                    int row = bm + wm + mi * 16 + quad * 4 + r;
                    int s = row & (SEQ - 1);
                    float ang = (float)s * invf;
                    float sn, cs;
                    __sincosf(ang, &sn, &cs);
                    float x1 = acc[mi][ni][r] + b1;
                    float x2 = acc[mi][ni + 2][r] + b2;
                    store_out(&out[(size_t)row * QKSTR + col], x1 * cs - x2 * sn);
                    store_out(&out[(size_t)row * QKSTR + col + 32], x2 * cs + x1 * sn);
                }
            }
        }
    } else if (MODE == 1) {
        // V columns: write transposed into vtg[(b*16+h)*64 + dh][s], 8B packed
#pragma unroll
        for (int ni = 0; ni < NI; ni++) {
            int colg = bn + wn + ni * 16 + l16;
            int vcol = colg - 2 * DMODEL;
            int hh = vcol >> 6, dh = vcol & 63;
            float bv = bias[colg];
#pragma unroll
            for (int mi = 0; mi < 2; mi++) {
                int row0 = bm + wm + mi * 16 + quad * 4;
                int bb = row0 >> 11;
                int ss = row0 & (SEQ - 1);
                __hip_bfloat16 tmp[4];
#pragma unroll
                for (int r = 0; r < 4; r++)
                    tmp[r] = __float2bfloat16(acc[mi][ni][r] + bv);
                *(uint2*)(vtg + (((size_t)bb * NHEADS + hh) * DHEAD + dh) * SEQ + ss) =
                    *(uint2*)tmp;
            }
        }
    } else {
#pragma unroll
        for (int mi = 0; mi < 2; mi++)
#pragma unroll
            for (int ni = 0; ni < NI; ni++) {
                int col = bn + wn + ni * 16 + l16;
                float bv = bias[col];
#pragma unroll
                for (int r = 0; r < 4; r++) {
                    int row = bm + wm + mi * 16 + quad * 4 + r;
                    store_out(&out[(size_t)row * N + col], acc[mi][ni][r] + bv);
                }
            }
    }
}

// ---------------------------------------------------------------------------
// MFMA flash attention v4: uniform-duration causal schedule.
// Block = q-tile pair (qa=y, qb=31-y), 8 waves. Old v3 ran jt=0..qb (17..32
// iterations, waves 0-3 idle for jt>qa -> 51% wave density, CU imbalance).
// v4: phase 1 (n<=qa): one shared k-tile, waves 0-3 on qa band w&3, waves 4-7
// on qb band w&3 (as v3). Phase 2 (qb's remaining qb-qa tiles, odd count):
// TWO k-tiles per iteration - waves 0-3 take the even tile into a second
// accumulator oacc2 (qb's Q frags), waves 4-7 the odd tile into oacc.
// Total = (qa+1) + (qb-qa+1)/2 = 17 iterations for EVERY block, all waves
// busy every iteration. Epilogue LDS-reduces oacc2 into waves 4-7.
// K/V staged through a 4-deep ring (2 consumed + 2 prefetched per phase-2
// iter); LDS 80 KB -> 2 blocks/CU, exactly matching the 512-block grid.
// Per wave per k-tile: 8 QK + 10 PV MFMAs (row-sum l via ones B-frag).
// exp(s/8) folded to exp2(s*0.18033688) (single v_mul + v_exp).
// ---------------------------------------------------------------------------
__global__ __launch_bounds__(512, 4) void flash_attn_mfma_kernel(
    const __hip_bfloat16* __restrict__ qkb,
    const __hip_bfloat16* __restrict__ vtg,
    __hip_bfloat16* __restrict__ ctx)
{
    const int bh = blockIdx.x;
    const int b = bh >> 4, h = bh & 15;
    const int y = blockIdx.y;               // 0..15
    const int qa = y, qb = 31 - y;          // qa < qb always (qa<=15, qb>=16)
    const int tid = threadIdx.x;
    const int w = tid >> 6;                 // 0..7
    const int lane = tid & 63;
    const int quad = lane >> 4;
    const int l16 = lane & 15;
    const int w4 = w & 3;                   // 16-row band within the q-tile
    const int grp = w >> 2;                 // 0: qa-group, 1: qb-group
    const int qtp = grp ? qb : qa;          // primary q-tile

    __shared__ alignas(16) __hip_bfloat16 Ks[4][64 * 64];  // 32 KB ring [key][dh] swz
    __shared__ alignas(16) __hip_bfloat16 Vt[4][64 * 64];  // 32 KB ring [dh][key] swz
    __shared__ alignas(16) __hip_bfloat16 Ps[128 * 64];    // 16 KB wave-private bands

    const __hip_bfloat16* qbase = qkb + (size_t)b * SEQ * QKSTR + h * DHEAD;
    const __hip_bfloat16* kbase = qbase + DMODEL;
    const __hip_bfloat16* vbase = vtg + (size_t)bh * DHEAD * SEQ;

    // Q A-frags: primary tile (qtp); secondary = qb (used by grp0 in phase 2)
    const __hip_bfloat16* qrowp = qbase + (size_t)(qtp * 64 + w4 * 16 + l16) * QKSTR;
    bf16x8 qp0 = *(const bf16x8*)(qrowp + quad * 8);
    bf16x8 qp1 = *(const bf16x8*)(qrowp + 32 + quad * 8);
    const __hip_bfloat16* qrows = qbase + (size_t)(qb * 64 + w4 * 16 + l16) * QKSTR;
    bf16x8 qs0 = *(const bf16x8*)(qrows + quad * 8);
    bf16x8 qs1 = *(const bf16x8*)(qrows + 32 + quad * 8);

    // staging: wave w stages rows [w*8, w*8+8) of K tile and of Vt tile
    const int srow = lane >> 3;
    const int gc8 = ((lane & 7) ^ srow) * 8;          // XOR swizzle, matches readers
    const __hip_bfloat16* kg = kbase + (size_t)(w * 8 + srow) * QKSTR + gc8;
    const __hip_bfloat16* vg = vbase + (size_t)(w * 8 + srow) * SEQ + gc8;

    // hoisted LDS frag offsets (tile-invariant)
    const int xr = l16 & 7;
    const int fo0 = l16 * 64 + ((quad ^ xr) << 3);          // kk=0 chunk term
    const int fo1 = l16 * 64 + (((4 + quad) ^ xr) << 3);    // kk=1
    const int pband = w * 16;
    const int pfo0 = (pband + l16) * 64 + ((quad ^ xr) << 3);
    const int pfo1 = (pband + l16) * 64 + (((4 + quad) ^ xr) << 3);

    const short onev = (l16 == 0) ? (short)0x3F80 : (short)0;
    const bf16x8 ones = {onev, onev, onev, onev, onev, onev, onev, onev};

    f32x4 oacc[5] = {};     // primary accumulator (grp0: qa; grp1: qb)
    f32x4 oacc2[5] = {};    // grp0's phase-2 partial for qb

    auto stage = [&](int t) {
        glds16(kg + (size_t)t * 64 * QKSTR, &Ks[t & 3][w * 512]);
        glds16(vg + t * 64, &Vt[t & 3][w * 512]);
    };

    auto compute = [&](const __hip_bfloat16* ks, const __hip_bfloat16* vs,
                       bf16x8 f0, bf16x8 f1, f32x4* oa, bool diag) {
        // S = Q K^T : 8 MFMAs for 16q x 64k
        f32x4 s4[4] = {};
#pragma unroll
        for (int nt = 0; nt < 4; nt++)
            s4[nt] = __builtin_amdgcn_mfma_f32_16x16x32_bf16(
                f0, *(const bf16x8*)(ks + nt * 1024 + fo0), s4[nt], 0, 0, 0);
#pragma unroll
        for (int nt = 0; nt < 4; nt++)
            s4[nt] = __builtin_amdgcn_mfma_f32_16x16x32_bf16(
                f1, *(const bf16x8*)(ks + nt * 1024 + fo1), s4[nt], 0, 0, 0);

        // p = exp(s/8) = exp2(s*0.18033688); mask only diagonal tile
#pragma unroll
        for (int nt = 0; nt < 4; nt++)
#pragma unroll
            for (int r = 0; r < 4; r++) {
                float p = exp2f(s4[nt][r] * 0.1803368801f);
                if (diag)
                    p = (nt * 16 + l16 <= w4 * 16 + quad * 4 + r) ? p : 0.f;
                int rr = quad * 4 + r;
                Ps[(pband + rr) * 64 +
                   (((nt * 2 + (l16 >> 3)) ^ (rr & 7)) << 3) + xr] =
                    __float2bfloat16(p);
            }

        // O += P V (ones-frag 5th tile accumulates l): 10 MFMAs
        bf16x8 pf0 = *(const bf16x8*)(Ps + pfo0);
        bf16x8 pf1 = *(const bf16x8*)(Ps + pfo1);
#pragma unroll
        for (int dt = 0; dt < 4; dt++)
            oa[dt] = __builtin_amdgcn_mfma_f32_16x16x32_bf16(
                pf0, *(const bf16x8*)(vs + dt * 1024 + fo0), oa[dt], 0, 0, 0);
        oa[4] = __builtin_amdgcn_mfma_f32_16x16x32_bf16(pf0, ones, oa[4], 0, 0, 0);
#pragma unroll
        for (int dt = 0; dt < 4; dt++)
            oa[dt] = __builtin_amdgcn_mfma_f32_16x16x32_bf16(
                pf1, *(const bf16x8*)(vs + dt * 1024 + fo1), oa[dt], 0, 0, 0);
        oa[4] = __builtin_amdgcn_mfma_f32_16x16x32_bf16(pf1, ones, oa[4], 0, 0, 0);
    };

    // prologue: stage tile 0
    stage(0);
    const int nit = qa + 1 + ((qb - qa + 1) >> 1);   // == 17 for all y

    for (int n = 0; n < nit; n++) {
        __syncthreads();                     // drains vmcnt: staged tiles ready
        // stage next iteration's tile(s); ring distance guarantees no overlap:
        // phase-2 iter consumes {T,T+1}, stages {T+2,T+3} - distinct mod 4.
        if (n < qa) {
            stage(n + 1);
        } else {
            int t0n = 2 * n - qa + 1;        // first tile of next phase-2 pair
            if (t0n <= qb) stage(t0n);
            if (t0n + 1 <= qb) stage(t0n + 1);
        }
        if (n <= qa) {
            // phase 1: shared k-tile n; grp0 -> qa, grp1 -> qb (primary acc)
            compute(&Ks[n & 3][0], &Vt[n & 3][0], qp0, qp1, oacc, n == qtp);
        } else {
            // phase 2: both groups on qb, two consecutive k-tiles
            int t = 2 * n - qa - 1 + grp;
            if (t <= qb) {
                if (grp) compute(&Ks[t & 3][0], &Vt[t & 3][0], qp0, qp1, oacc, t == qb);
                else     compute(&Ks[t & 3][0], &Vt[t & 3][0], qs0, qs1, oacc2, t == qb);
            }
        }
    }

    // epilogue: l sits in oa[4][r] at lanes l16==0 of each quad
    auto write_ctx = [&](f32x4* oa, int qt) {
#pragma unroll
        for (int r = 0; r < 4; r++) {
            float lv = __shfl(oa[4][r], lane & 48);
            float il = 1.0f / lv;
            int qg = qt * 64 + w4 * 16 + quad * 4 + r;
            __hip_bfloat16* op = ctx + (((size_t)b * SEQ + qg) * NHEADS + h) * DHEAD + l16;
#pragma unroll
            for (int dt = 0; dt < 4; dt++)
                op[dt * 16] = __float2bfloat16(oa[dt][r] * il);
        }
    };

    __syncthreads();                         // all K/V reads done; Ks reusable
    f32x4* red = (f32x4*)&Ks[0][0];          // 20 KB scratch for qb partials
    if (!grp) {
        f32x4* rp = red + ((w * 64 + lane) * 5);
#pragma unroll
        for (int i = 0; i < 5; i++) rp[i] = oacc2[i];
        write_ctx(oacc, qa);                 // qa output complete in phase 1
    }
    __syncthreads();
    if (grp) {
        f32x4* rp = red + (((w - 4) * 64 + lane) * 5);
#pragma unroll
        for (int i = 0; i < 5; i++) oacc[i] += rp[i];
        write_ctx(oacc, qb);                 // qb = waves 4-7 acc + partner partial
    }
}

// ---------------------------------------------------------------------------
extern "C" void kernel_launch(void* const* d_in, const int* in_sizes, int n_in,
                              void* d_out, int out_size, void* d_ws, size_t ws_size,
                              hipStream_t stream)
{
    const float* x      = (const float*)d_in[0];   // [2,2048,1024]
    const float* qkv_w  = (const float*)d_in[1];   // [3072,1024]
    const float* qkv_b  = (const float*)d_in[2];   // [3072]
    const float* proj_w = (const float*)d_in[3];   // [1024,1024]
    const float* proj_b = (const float*)d_in[4];   // [1024]
    float* out = (float*)d_out;                    // [2,2048,1024]

    char* w = (char*)d_ws;
    __hip_bfloat16* qkb = (__hip_bfloat16*)w;  w += (size_t)MTOT * QKSTR * 2;         // 16 MB
    __hip_bfloat16* vtg = (__hip_bfloat16*)w;  w += (size_t)MTOT * DMODEL * 2;        //  8 MB
    __hip_bfloat16* ctx = (__hip_bfloat16*)w;  w += (size_t)MTOT * DMODEL * 2;        //  8 MB
    __hip_bfloat16* xb  = (__hip_bfloat16*)w;  w += (size_t)MTOT * DMODEL * 2;        //  8 MB
    __hip_bfloat16* wqk = (__hip_bfloat16*)w;  w += (size_t)3 * DMODEL * DMODEL * 2;  //  6 MB
    __hip_bfloat16* wpr = (__hip_bfloat16*)w;                                         //  2 MB

    const int na4 = MTOT * DMODEL / 4;
    const int nb4 = 3 * DMODEL * DMODEL / 4;
    const int nc4 = DMODEL * DMODEL / 4;

    // 0) fused bf16 casts
    cast_all_kernel<<<(na4 + nb4 + nc4 + 255) / 256, 256, 0, stream>>>(
        x, xb, na4, qkv_w, wqk, nb4, proj_w, wpr, nc4);

    // 1) qkv projection: q,k (RoPE'd) -> qkb; V -> vtg (transposed), fused
    //    64x128 tiles -> 1536 blocks = 6/CU
    gemm_bias_kernel<__hip_bfloat16, 1, 128>
        <<<dim3(MTOT / GTM, (3 * DMODEL) / 128), 256, 0, stream>>>(
        xb, wqk, qkv_b, qkb, vtg, MTOT, 3 * DMODEL, DMODEL);

    // 2) causal MFMA flash attention -> ctx [B,S,H,Dh] bf16
    flash_attn_mfma_kernel<<<dim3(BATCH * NHEADS, 16), 512, 0, stream>>>(qkb, vtg, ctx);

    // 3) out = ctx @ proj_w^T + proj_b -> fp32 d_out
    //    64x64 tiles -> 1024 blocks = 4/CU
    gemm_bias_kernel<float, 0, 64>
        <<<dim3(MTOT / GTM, DMODEL / 64), 256, 0, stream>>>(
        ctx, wpr, proj_b, out, nullptr, MTOT, DMODEL, DMODEL);
}

// Round 2
// 172.029 us; speedup vs baseline: 1.0191x; 1.0191x over previous
//
#include <hip/hip_runtime.h>
#include <hip/hip_bf16.h>

// Problem constants
#define BATCH 2
#define SEQ   2048
#define DMODEL 1024
#define NHEADS 16
#define DHEAD  64
#define MTOT   (BATCH * SEQ)         // 4096 rows
#define QKSTR  2048                  // q,k buffer row stride (v stored separately)

typedef __attribute__((ext_vector_type(8))) short bf16x8;   // 8 bf16 in 4 VGPRs
typedef __attribute__((ext_vector_type(4))) float f32x4;

// 16B async global->LDS copy (LDS dest = wave-uniform base + lane*16).
__device__ __forceinline__ void glds16(const void* g, void* l)
{
    __builtin_amdgcn_global_load_lds(
        (const __attribute__((address_space(1))) unsigned int*)g,
        (__attribute__((address_space(3))) unsigned int*)l, 16, 0, 0);
}

// ---------------------------------------------------------------------------
// fused fp32 -> bf16 casts (x, qkv_w, proj_w in one launch)
// ---------------------------------------------------------------------------
__global__ void cast_all_kernel(
    const float* __restrict__ a, __hip_bfloat16* __restrict__ oa, int na4,
    const float* __restrict__ b, __hip_bfloat16* __restrict__ ob, int nb4,
    const float* __restrict__ c, __hip_bfloat16* __restrict__ oc, int nc4)
{
    int i = blockIdx.x * blockDim.x + threadIdx.x;
    const float* src; __hip_bfloat16* dst; int j = i;
    if (j < na4) { src = a; dst = oa; }
    else {
        j -= na4;
        if (j < nb4) { src = b; dst = ob; }
        else {
            j -= nb4;
            if (j >= nc4) return;
            src = c; dst = oc;
        }
    }
    float4 v = ((const float4*)src)[j];
    __hip_bfloat16 tmp[4];
    tmp[0] = __float2bfloat16(v.x);
    tmp[1] = __float2bfloat16(v.y);
    tmp[2] = __float2bfloat16(v.z);
    tmp[3] = __float2bfloat16(v.w);
    *(uint2*)(dst + 4 * (size_t)j) = *(const uint2*)tmp;
}

// ---------------------------------------------------------------------------
// GEMM: out[M,N] = A[M,K] @ W[N,K]^T + bias[N]; bf16 in, fp32 acc.
// 64xTN tile, BK=64, global_load_lds(16B) staging, XOR-swizzled LDS.
// MODE 0: plain store (stride N). MODE 1 (qkv, TN=128): cols<2048 RoPE pairs
// into qk buffer (stride QKSTR); cols>=2048 V transposed to vtg[(b,h),dh,s].
// ---------------------------------------------------------------------------
#define GTM 64
#define GBK 64

__device__ __forceinline__ void store_out(float* p, float v) { *p = v; }
__device__ __forceinline__ void store_out(__hip_bfloat16* p, float v) { *p = __float2bfloat16(v); }

template <typename OutT, int MODE, int TN>
__global__ __launch_bounds__(256, 6) void gemm_bias_kernel(
    const __hip_bfloat16* __restrict__ A, const __hip_bfloat16* __restrict__ W,
    const float* __restrict__ bias, OutT* __restrict__ out,
    __hip_bfloat16* __restrict__ vtg,
    int M, int N, int K)
{
    const int NI = TN / 32;                    // n-frags per wave
    const int bm = blockIdx.x * GTM;
    const int bn = blockIdx.y * TN;
    const int tid = threadIdx.x;
    const int wave = tid >> 6;
    const int lane = tid & 63;
    const int quad = lane >> 4;
    const int l16 = lane & 15;
    const int wm = (wave & 1) * 32;
    const int wn = (wave >> 1) * (TN / 2);

    __shared__ __hip_bfloat16 As[GTM * GBK];   // 8 KB
    __shared__ __hip_bfloat16 Bs[TN * GBK];    // 16 KB (TN=128) / 8 KB (TN=64)

    f32x4 acc[2][NI] = {};

    const int srow = lane >> 3;
    const int gc8 = (((lane & 7) ^ srow)) * 8;

    for (int kt = 0; kt < K; kt += GBK) {
#pragma unroll
        for (int t = 0; t < 2; t++) {          // A: 8 chunks of 8 rows, 2/wave
            int i = wave * 2 + t;
            glds16(A + (size_t)(bm + i * 8 + srow) * K + kt + gc8, As + i * 512);
        }
#pragma unroll
        for (int t = 0; t < TN / 32; t++) {    // B: TN/8 chunks, (TN/32)/wave
            int i = wave * (TN / 32) + t;
            glds16(W + (size_t)(bn + i * 8 + srow) * K + kt + gc8, Bs + i * 512);
        }
        __syncthreads();

#pragma unroll
        for (int kk = 0; kk < 2; kk++) {
            bf16x8 af[2], bfr[NI];
#pragma unroll
            for (int i = 0; i < 2; i++) {
                int ra = wm + i * 16 + l16;
                af[i] = *(const bf16x8*)(As + ra * 64 + (((kk << 2) + quad) ^ (ra & 7)) * 8);
            }
#pragma unroll
            for (int i = 0; i < NI; i++) {
                int rb = wn + i * 16 + l16;
                bfr[i] = *(const bf16x8*)(Bs + rb * 64 + (((kk << 2) + quad) ^ (rb & 7)) * 8);
            }
#pragma unroll
            for (int mi = 0; mi < 2; mi++)
#pragma unroll
                for (int ni = 0; ni < NI; ni++)
                    acc[mi][ni] = __builtin_amdgcn_mfma_f32_16x16x32_bf16(
                        af[mi], bfr[ni], acc[mi][ni], 0, 0, 0);
        }
        __syncthreads();
    }

    if (MODE == 1 && (bn + wn) < 2 * DMODEL) {
        // q/k columns: RoPE pairs (dh, dh+32) = (acc[.][ni], acc[.][ni+2])
#pragma unroll
        for (int ni = 0; ni < 2; ni++) {
            int col = bn + wn + ni * 16 + l16;
            int i32 = col & 31;
            float invf = exp2f(-13.287712379549449f * (float)i32 * (1.0f / 32.0f));
            float b1 = bias[col], b2 = bias[col + 32];
#pragma unroll
            for (int mi = 0; mi < 2; mi++) {
#pragma unroll
                for (int r = 0; r < 4; r++) {
                    int row = bm + wm + mi * 16 + quad * 4 + r;
                    int s = row & (SEQ - 1);
                    float ang = (float)s * invf;
                    float sn, cs;
                    __sincosf(ang, &sn, &cs);
                    float x1 = acc[mi][ni][r] + b1;
                    float x2 = acc[mi][ni + 2][r] + b2;
                    store_out(&out[(size_t)row * QKSTR + col], x1 * cs - x2 * sn);
                    store_out(&out[(size_t)row * QKSTR + col + 32], x2 * cs + x1 * sn);
                }
            }
        }
    } else if (MODE == 1) {
        // V columns: write transposed into vtg[(b*16+h)*64 + dh][s], 8B packed
#pragma unroll
        for (int ni = 0; ni < NI; ni++) {
            int colg = bn + wn + ni * 16 + l16;
            int vcol = colg - 2 * DMODEL;
            int hh = vcol >> 6, dh = vcol & 63;
            float bv = bias[colg];
#pragma unroll
            for (int mi = 0; mi < 2; mi++) {
                int row0 = bm + wm + mi * 16 + quad * 4;
                int bb = row0 >> 11;
                int ss = row0 & (SEQ - 1);
                __hip_bfloat16 tmp[4];
#pragma unroll
                for (int r = 0; r < 4; r++)
                    tmp[r] = __float2bfloat16(acc[mi][ni][r] + bv);
                *(uint2*)(vtg + (((size_t)bb * NHEADS + hh) * DHEAD + dh) * SEQ + ss) =
                    *(uint2*)tmp;
            }
        }
    } else {
#pragma unroll
        for (int mi = 0; mi < 2; mi++)
#pragma unroll
            for (int ni = 0; ni < NI; ni++) {
                int col = bn + wn + ni * 16 + l16;
                float bv = bias[col];
#pragma unroll
                for (int r = 0; r < 4; r++) {
                    int row = bm + wm + mi * 16 + quad * 4 + r;
                    store_out(&out[(size_t)row * N + col], acc[mi][ni][r] + bv);
                }
            }
    }
}

// ---------------------------------------------------------------------------
// MFMA flash attention v5: uniform 17-iteration schedule, SINGLE accumulator.
// v4 post-mortem: passing f32x4* oa (runtime pointer) demoted accumulators to
// scratch (rule #20) -> +5MB HBM writes, slower. v5 keeps one statically-named
// oacc[5] per thread: grp0's qa output is COMPLETE after phase-1 iter n==qa,
// so grp0 writes qa ctx mid-kernel, zeroes oacc, switches Q-frags to qb, and
// phase 2 accumulates qb partials into the same registers. Epilogue: grp0
// passes its qb partial via LDS, grp1 adds and writes qb.
// Phase 1 (n<=qa): one shared k-tile, both groups on own q-tile.
// Phase 2: two k-tiles/iter (grp0 even, grp1 odd; grp1 idles final iter).
// Total = 17 iterations for every block. K/V 4-deep ring (80 KB LDS,
// 2 blocks/CU = the 512-block grid residency).
// Per wave per k-tile: 8 QK + 10 PV MFMAs (row-sum l via ones B-frag).
// ---------------------------------------------------------------------------
__global__ __launch_bounds__(512, 4) void flash_attn_mfma_kernel(
    const __hip_bfloat16* __restrict__ qkb,
    const __hip_bfloat16* __restrict__ vtg,
    __hip_bfloat16* __restrict__ ctx)
{
    const int bh = blockIdx.x;
    const int b = bh >> 4, h = bh & 15;
    const int y = blockIdx.y;               // 0..15
    const int qa = y, qb = 31 - y;          // qa < qb always (qa<=15, qb>=16)
    const int tid = threadIdx.x;
    const int w = tid >> 6;                 // 0..7
    const int lane = tid & 63;
    const int quad = lane >> 4;
    const int l16 = lane & 15;
    const int w4 = w & 3;                   // 16-row band within the q-tile
    const int grp = w >> 2;                 // 0: qa-group, 1: qb-group
    const int qtp = grp ? qb : qa;          // primary q-tile

    __shared__ alignas(16) __hip_bfloat16 Ks[4][64 * 64];  // 32 KB ring [key][dh] swz
    __shared__ alignas(16) __hip_bfloat16 Vt[4][64 * 64];  // 32 KB ring [dh][key] swz
    __shared__ alignas(16) __hip_bfloat16 Ps[128 * 64];    // 16 KB wave-private bands

    const __hip_bfloat16* qbase = qkb + (size_t)b * SEQ * QKSTR + h * DHEAD;
    const __hip_bfloat16* kbase = qbase + DMODEL;
    const __hip_bfloat16* vbase = vtg + (size_t)bh * DHEAD * SEQ;

    // Q A-frags: primary (qtp); secondary = qb (grp0 switches to it after phase 1)
    const __hip_bfloat16* qrowp = qbase + (size_t)(qtp * 64 + w4 * 16 + l16) * QKSTR;
    bf16x8 qp0 = *(const bf16x8*)(qrowp + quad * 8);
    bf16x8 qp1 = *(const bf16x8*)(qrowp + 32 + quad * 8);
    const __hip_bfloat16* qrows = qbase + (size_t)(qb * 64 + w4 * 16 + l16) * QKSTR;
    bf16x8 qs0 = *(const bf16x8*)(qrows + quad * 8);
    bf16x8 qs1 = *(const bf16x8*)(qrows + 32 + quad * 8);

    // staging: wave w stages rows [w*8, w*8+8) of K tile and of Vt tile
    const int srow = lane >> 3;
    const int gc8 = ((lane & 7) ^ srow) * 8;          // XOR swizzle, matches readers
    const __hip_bfloat16* kg = kbase + (size_t)(w * 8 + srow) * QKSTR + gc8;
    const __hip_bfloat16* vg = vbase + (size_t)(w * 8 + srow) * SEQ + gc8;

    // hoisted LDS frag offsets (tile-invariant)
    const int xr = l16 & 7;
    const int fo0 = l16 * 64 + ((quad ^ xr) << 3);          // kk=0 chunk term
    const int fo1 = l16 * 64 + (((4 + quad) ^ xr) << 3);    // kk=1
    const int pband = w * 16;
    const int pfo0 = (pband + l16) * 64 + ((quad ^ xr) << 3);
    const int pfo1 = (pband + l16) * 64 + (((4 + quad) ^ xr) << 3);

    const short onev = (l16 == 0) ? (short)0x3F80 : (short)0;
    const bf16x8 ones = {onev, onev, onev, onev, onev, onev, onev, onev};

    f32x4 oacc[5] = {};     // THE accumulator (grp0: qa then qb-partial; grp1: qb)

    auto stage = [&](int t) {
        glds16(kg + (size_t)t * 64 * QKSTR, &Ks[t & 3][w * 512]);
        glds16(vg + t * 64, &Vt[t & 3][w * 512]);
    };

    // compute one 16q x 64k tile into oacc (captured statically -> registers)
    auto compute = [&](const __hip_bfloat16* ks, const __hip_bfloat16* vs, bool diag) {
        // S = Q K^T : 8 MFMAs
        f32x4 s4[4] = {};
#pragma unroll
        for (int nt = 0; nt < 4; nt++)
            s4[nt] = __builtin_amdgcn_mfma_f32_16x16x32_bf16(
                qp0, *(const bf16x8*)(ks + nt * 1024 + fo0), s4[nt], 0, 0, 0);
#pragma unroll
        for (int nt = 0; nt < 4; nt++)
            s4[nt] = __builtin_amdgcn_mfma_f32_16x16x32_bf16(
                qp1, *(const bf16x8*)(ks + nt * 1024 + fo1), s4[nt], 0, 0, 0);

        // p = exp(s/8) = exp2(s*0.18033688); diag tile masks upper triangle
        if (diag) {
#pragma unroll
            for (int nt = 0; nt < 4; nt++)
#pragma unroll
                for (int r = 0; r < 4; r++) {
                    float p = exp2f(s4[nt][r] * 0.1803368801f);
                    p = (nt * 16 + l16 <= w4 * 16 + quad * 4 + r) ? p : 0.f;
                    int rr = quad * 4 + r;
                    Ps[(pband + rr) * 64 +
                       (((nt * 2 + (l16 >> 3)) ^ (rr & 7)) << 3) + xr] =
                        __float2bfloat16(p);
                }
        } else {
#pragma unroll
            for (int nt = 0; nt < 4; nt++)
#pragma unroll
                for (int r = 0; r < 4; r++) {
                    float p = exp2f(s4[nt][r] * 0.1803368801f);
                    int rr = quad * 4 + r;
                    Ps[(pband + rr) * 64 +
                       (((nt * 2 + (l16 >> 3)) ^ (rr & 7)) << 3) + xr] =
                        __float2bfloat16(p);
                }
        }

        // O += P V (ones-frag 5th tile accumulates l): 10 MFMAs
        bf16x8 pf0 = *(const bf16x8*)(Ps + pfo0);
        bf16x8 pf1 = *(const bf16x8*)(Ps + pfo1);
#pragma unroll
        for (int dt = 0; dt < 4; dt++)
            oacc[dt] = __builtin_amdgcn_mfma_f32_16x16x32_bf16(
                pf0, *(const bf16x8*)(vs + dt * 1024 + fo0), oacc[dt], 0, 0, 0);
        oacc[4] = __builtin_amdgcn_mfma_f32_16x16x32_bf16(pf0, ones, oacc[4], 0, 0, 0);
#pragma unroll
        for (int dt = 0; dt < 4; dt++)
            oacc[dt] = __builtin_amdgcn_mfma_f32_16x16x32_bf16(
                pf1, *(const bf16x8*)(vs + dt * 1024 + fo1), oacc[dt], 0, 0, 0);
        oacc[4] = __builtin_amdgcn_mfma_f32_16x16x32_bf16(pf1, ones, oacc[4], 0, 0, 0);
    };

    // epilogue helper: l sits in oacc[4][r] at lanes l16==0 of each quad
    auto write_ctx = [&](int qt) {
#pragma unroll
        for (int r = 0; r < 4; r++) {
            float lv = __shfl(oacc[4][r], lane & 48);
            float il = 1.0f / lv;
            int qg = qt * 64 + w4 * 16 + quad * 4 + r;
            __hip_bfloat16* op = ctx + (((size_t)b * SEQ + qg) * NHEADS + h) * DHEAD + l16;
#pragma unroll
            for (int dt = 0; dt < 4; dt++)
                op[dt * 16] = __float2bfloat16(oacc[dt][r] * il);
        }
    };

    // prologue: stage tile 0
    stage(0);
    const int nit = qa + 1 + ((qb - qa + 1) >> 1);   // == 17 for all y

    for (int n = 0; n < nit; n++) {
        __syncthreads();                     // staged tiles for this iter ready
        // stage next iteration's tile(s); ring distance 4 guarantees no overlap
        if (n < qa) {
            stage(n + 1);
        } else {
            int t0n = 2 * n - qa + 1;        // first tile of next phase-2 pair
            if (t0n <= qb) stage(t0n);
            if (t0n + 1 <= qb) stage(t0n + 1);
        }
        if (n <= qa) {
            // phase 1: shared k-tile n; both groups on own q-tile
            compute(&Ks[n & 3][0], &Vt[n & 3][0], n == qtp);
            if (n == qa && !grp) {
                // grp0's qa output complete: write it, reuse oacc for qb partial
                write_ctx(qa);
#pragma unroll
                for (int i = 0; i < 5; i++) oacc[i] = f32x4{0.f, 0.f, 0.f, 0.f};
                qp0 = qs0; qp1 = qs1;        // switch to qb's Q-frags
            }
        } else {
            // phase 2: both groups on qb, two consecutive k-tiles
            int t = 2 * n - qa - 1 + grp;
            if (t <= qb)
                compute(&Ks[t & 3][0], &Vt[t & 3][0], t == qb);
        }
    }

    // epilogue: combine qb partials (grp0 -> LDS -> grp1 adds, writes qb)
    __syncthreads();                         // all K/V LDS reads done; Ks reusable
    f32x4* red = (f32x4*)&Ks[0][0];          // 20 KB scratch
    if (!grp) {
        f32x4* rp = red + ((w * 64 + lane) * 5);
#pragma unroll
        for (int i = 0; i < 5; i++) rp[i] = oacc[i];
    }
    __syncthreads();
    if (grp) {
        f32x4* rp = red + (((w - 4) * 64 + lane) * 5);
#pragma unroll
        for (int i = 0; i < 5; i++) oacc[i] += rp[i];
        write_ctx(qb);
    }
}

// ---------------------------------------------------------------------------
extern "C" void kernel_launch(void* const* d_in, const int* in_sizes, int n_in,
                              void* d_out, int out_size, void* d_ws, size_t ws_size,
                              hipStream_t stream)
{
    const float* x      = (const float*)d_in[0];   // [2,2048,1024]
    const float* qkv_w  = (const float*)d_in[1];   // [3072,1024]
    const float* qkv_b  = (const float*)d_in[2];   // [3072]
    const float* proj_w = (const float*)d_in[3];   // [1024,1024]
    const float* proj_b = (const float*)d_in[4];   // [1024]
    float* out = (float*)d_out;                    // [2,2048,1024]

    char* w = (char*)d_ws;
    __hip_bfloat16* qkb = (__hip_bfloat16*)w;  w += (size_t)MTOT * QKSTR * 2;         // 16 MB
    __hip_bfloat16* vtg = (__hip_bfloat16*)w;  w += (size_t)MTOT * DMODEL * 2;        //  8 MB
    __hip_bfloat16* ctx = (__hip_bfloat16*)w;  w += (size_t)MTOT * DMODEL * 2;        //  8 MB
    __hip_bfloat16* xb  = (__hip_bfloat16*)w;  w += (size_t)MTOT * DMODEL * 2;        //  8 MB
    __hip_bfloat16* wqk = (__hip_bfloat16*)w;  w += (size_t)3 * DMODEL * DMODEL * 2;  //  6 MB
    __hip_bfloat16* wpr = (__hip_bfloat16*)w;                                         //  2 MB

    const int na4 = MTOT * DMODEL / 4;
    const int nb4 = 3 * DMODEL * DMODEL / 4;
    const int nc4 = DMODEL * DMODEL / 4;

    // 0) fused bf16 casts
    cast_all_kernel<<<(na4 + nb4 + nc4 + 255) / 256, 256, 0, stream>>>(
        x, xb, na4, qkv_w, wqk, nb4, proj_w, wpr, nc4);

    // 1) qkv projection: q,k (RoPE'd) -> qkb; V -> vtg (transposed), fused
    //    64x128 tiles -> 1536 blocks = 6/CU
    gemm_bias_kernel<__hip_bfloat16, 1, 128>
        <<<dim3(MTOT / GTM, (3 * DMODEL) / 128), 256, 0, stream>>>(
        xb, wqk, qkv_b, qkb, vtg, MTOT, 3 * DMODEL, DMODEL);

    // 2) causal MFMA flash attention -> ctx [B,S,H,Dh] bf16
    flash_attn_mfma_kernel<<<dim3(BATCH * NHEADS, 16), 512, 0, stream>>>(qkb, vtg, ctx);

    // 3) out = ctx @ proj_w^T + proj_b -> fp32 d_out
    //    64x64 tiles -> 1024 blocks = 4/CU
    gemm_bias_kernel<float, 0, 64>
        <<<dim3(MTOT / GTM, DMODEL / 64), 256, 0, stream>>>(
        ctx, wpr, proj_b, out, nullptr, MTOT, DMODEL, DMODEL);
}